// Round 6
// baseline (476.177 us; speedup 1.0000x reference)
//
#include <hip/hip_runtime.h>
#include <hip/hip_cooperative_groups.h>

namespace cg = cooperative_groups;

#define NB 32
#define NN 500
#define HIN 64
#define HHID 16
#define NHEAD 8
#define NVALID 400
#define MAXK 128
#define NEG_INF -1e20f
#define BLK 512
#define RPX 2000   // rows per XCD = 4 batches

union SMem {
    float w1s[8192];                                                                  // 32 KB, [f][h*16+o]
    float w2s[8192];                                                                  // 32 KB, [j][o]
    struct { int nb[8][MAXK]; float p[8][NHEAD][MAXK + 1]; float inv[8][NHEAD]; } a1; // 37.4 KB
    struct { int nb[8][MAXK]; float p[8][MAXK]; } a2;                                 // 8 KB
    struct { float attn[NN]; float red[8]; float part[8][64]; } pl;                   // 4 KB
};

__global__ __launch_bounds__(BLK, 4) void k_fused(
    const float* __restrict__ x, const float* __restrict__ A,
    const float* __restrict__ w1, const float* __restrict__ as1, const float* __restrict__ ad1,
    const float* __restrict__ w2, const float* __restrict__ as2, const float* __restrict__ ad2,
    const float* __restrict__ aw,
    int* __restrict__ nbr, int* __restrict__ cnt,
    float* __restrict__ h1p, float* __restrict__ e1s, float* __restrict__ e1d,
    float* __restrict__ h1cat, float* __restrict__ h2p,
    float* __restrict__ e2s, float* __restrict__ e2d,
    float* __restrict__ xc, float* __restrict__ sc, float* __restrict__ rootd,
    float* __restrict__ out)
{
    cg::grid_group gg = cg::this_grid();
    int t = threadIdx.x, wv = t >> 6, lane = t & 63;
    // XCD-tiled row mapping: blocks with blockIdx%8==xcd handle rows [xcd*RPX, xcd*RPX+RPX)
    int xcd = blockIdx.x & 7;
    int lw = (blockIdx.x >> 3) * 8 + wv;          // local wave id within xcd
    int wpx = (gridDim.x >> 3) * 8;               // waves per xcd
    int row0 = xcd * RPX;
    __shared__ SMem sm;

    // ---- stage w1 into LDS: w1s[f*128 + h*16 + o] ----
    for (int i = t; i < 8192; i += BLK) {
        int h = i >> 10, f = (i >> 4) & 63, o = i & 15;
        sm.w1s[f * 128 + h * 16 + o] = w1[i];
    }

    // ---------- phase 1: neighbor-list build (wave per row, ballot compaction) ----------
    for (int r = lw; r < RPX; r += wpx) {
        int row = row0 + r;
        const float* ar = A + (size_t)row * NN;
        int c = 0;
        for (int it = 0; it < 8; ++it) {
            int m = it * 64 + lane;
            bool v = (m < NN) && (ar[m] > 0.f);
            unsigned long long bal = __ballot(v);
            if (v) {
                int pos = c + __popcll(bal & ((1ull << lane) - 1ull));
                if (pos < MAXK) nbr[(size_t)row * MAXK + pos] = m;
            }
            c += (int)__popcll(bal);
        }
        if (lane == 0) cnt[row] = c < MAXK ? c : MAXK;
    }
    __syncthreads();   // w1s staging visible

    // ---------- phase 2: layer-1 projection + e (wave per row; h1p [b][n][128], e1 [b][n][8]) ----------
    for (int r = lw; r < RPX; r += wpx) {
        int row = row0 + r;
        const float4* xp4 = (const float4*)(x + (size_t)row * HIN);
#pragma unroll
        for (int rr = 0; rr < 2; ++rr) {
            int oi = rr * 64 + lane;              // oi = h*16+o
            int h = oi >> 4, o = lane & 15;
            const float* wp = sm.w1s + oi;
            float acc = 0.f;
#pragma unroll
            for (int f4 = 0; f4 < 16; ++f4) {
                float4 u = xp4[f4];
                acc += u.x * wp[(f4 * 4 + 0) * 128] + u.y * wp[(f4 * 4 + 1) * 128]
                     + u.z * wp[(f4 * 4 + 2) * 128] + u.w * wp[(f4 * 4 + 3) * 128];
            }
            h1p[(size_t)row * 128 + oi] = acc;
            float vs = acc * as1[oi], vd = acc * ad1[oi];
#pragma unroll
            for (int m = 1; m < 16; m <<= 1) { vs += __shfl_xor(vs, m); vd += __shfl_xor(vd, m); }
            if (o == 0) {
                e1s[(size_t)row * 8 + h] = vs;
                e1d[(size_t)row * 8 + h] = vd;
            }
        }
    }
    gg.sync();

    // ---------- phase 3: layer-1 sparse softmax + aggregate + ELU (wave per row) ----------
    for (int r = lw; r < RPX; r += wpx) {
        int row = row0 + r;
        int b = row / NN;
        int K = cnt[row];
        for (int k = lane; k < K; k += 64) sm.a1.nb[wv][k] = nbr[(size_t)row * MAXK + k];
        float esh[NHEAD];
#pragma unroll
        for (int h = 0; h < NHEAD; ++h) esh[h] = e1s[(size_t)row * 8 + h];
        for (int k = lane; k < K; k += 64) {
            const float* ed8 = e1d + ((size_t)b * NN + sm.a1.nb[wv][k]) * 8;
#pragma unroll
            for (int h = 0; h < NHEAD; ++h) {
                float e = esh[h] + ed8[h];
                sm.a1.p[wv][h][k] = e > 0.f ? e : 0.2f * e;
            }
        }
        for (int h = 0; h < NHEAD; ++h) {
            float m = -1e30f;
            for (int k = lane; k < K; k += 64) m = fmaxf(m, sm.a1.p[wv][h][k]);
#pragma unroll
            for (int mm = 1; mm < 64; mm <<= 1) m = fmaxf(m, __shfl_xor(m, mm));
            float s = 0.f;
            for (int k = lane; k < K; k += 64) {
                float v = __expf(sm.a1.p[wv][h][k] - m);
                sm.a1.p[wv][h][k] = v;
                s += v;
            }
#pragma unroll
            for (int mm = 1; mm < 64; mm <<= 1) s += __shfl_xor(s, mm);
            if (lane == 0) sm.a1.inv[wv][h] = 1.f / s;
        }
#pragma unroll
        for (int rr = 0; rr < 2; ++rr) {
            int oi = rr * 64 + lane;
            int h = oi >> 4;
            const float* hp = h1p + (size_t)b * NN * 128 + oi;   // gather: 512B contiguous per nbr
            const float* pp = sm.a1.p[wv][h];
            const int* nbp = sm.a1.nb[wv];
            float acc = 0.f;
            int k = 0;
            for (; k + 4 <= K; k += 4) {
                float p0 = pp[k], p1 = pp[k + 1], p2 = pp[k + 2], p3 = pp[k + 3];
                int m0 = nbp[k], m1 = nbp[k + 1], m2 = nbp[k + 2], m3 = nbp[k + 3];
                acc += p0 * hp[(size_t)m0 * 128] + p1 * hp[(size_t)m1 * 128]
                     + p2 * hp[(size_t)m2 * 128] + p3 * hp[(size_t)m3 * 128];
            }
            for (; k < K; ++k) acc += pp[k] * hp[(size_t)nbp[k] * 128];
            acc *= sm.a1.inv[wv][h];
            float v = acc > 0.f ? acc : expm1f(acc);    // ELU
            h1cat[(size_t)row * 128 + oi] = v;
        }
    }
    gg.sync();

    // ---------- phase 4: layer-2 projection + e2 (wave per row, weights in LDS) ----------
    for (int i = t; i < 8192; i += BLK) sm.w2s[i] = w2[i];
    __syncthreads();
    for (int r = lw; r < RPX; r += wpx) {
        int row = row0 + r;
        const float4* hp4 = (const float4*)(h1cat + (size_t)row * 128);
        const float* wp = sm.w2s + lane;
        float acc = 0.f;
#pragma unroll 8
        for (int j4 = 0; j4 < 32; ++j4) {
            float4 u = hp4[j4];
            acc += u.x * wp[(j4 * 4 + 0) * 64] + u.y * wp[(j4 * 4 + 1) * 64]
                 + u.z * wp[(j4 * 4 + 2) * 64] + u.w * wp[(j4 * 4 + 3) * 64];
        }
        h2p[(size_t)row * 64 + lane] = acc;
        float vs = acc * as2[lane], vd = acc * ad2[lane];
#pragma unroll
        for (int m = 1; m < 64; m <<= 1) { vs += __shfl_xor(vs, m); vd += __shfl_xor(vd, m); }
        if (lane == 0) { e2s[row] = vs; e2d[row] = vd; }
    }
    gg.sync();

    // ---------- phase 5: layer-2 sparse softmax + aggregate + fused score dots ----------
    for (int r = lw; r < RPX; r += wpx) {
        int row = row0 + r;
        int b = row / NN, n = row - b * NN;
        if (n >= NVALID) { xc[(size_t)row * 64 + lane] = 0.f; continue; }   // padded rows exactly 0
        int K = cnt[row];
        const int* nbg = nbr + (size_t)row * MAXK;
        int i0 = (lane < K) ? nbg[lane] : 0;
        int i1 = (lane + 64 < K) ? nbg[lane + 64] : 0;
        sm.a2.nb[wv][lane] = i0; sm.a2.nb[wv][lane + 64] = i1;
        float es = e2s[row];
        const float* ed = e2d + b * NN;
        float e0 = -1e30f, e1v = -1e30f;
        if (lane < K)      { float e = es + ed[i0]; e0 = e > 0.f ? e : 0.2f * e; }
        if (lane + 64 < K) { float e = es + ed[i1]; e1v = e > 0.f ? e : 0.2f * e; }
        float m = fmaxf(e0, e1v);
#pragma unroll
        for (int mm = 1; mm < 64; mm <<= 1) m = fmaxf(m, __shfl_xor(m, mm));
        float s0 = (lane < K) ? __expf(e0 - m) : 0.f;
        float s1 = (lane + 64 < K) ? __expf(e1v - m) : 0.f;
        float ss = s0 + s1;
#pragma unroll
        for (int mm = 1; mm < 64; mm <<= 1) ss += __shfl_xor(ss, mm);
        float inv = 1.f / ss;
        sm.a2.p[wv][lane] = s0 * inv; sm.a2.p[wv][lane + 64] = s1 * inv;
        const float* h2b = h2p + (size_t)b * NN * 64 + lane;
        const float* pp = sm.a2.p[wv];
        const int* nbp = sm.a2.nb[wv];
        float acc = 0.f;
        int k = 0;
        for (; k + 4 <= K; k += 4) {
            float p0 = pp[k], p1 = pp[k + 1], p2 = pp[k + 2], p3 = pp[k + 3];
            int m0 = nbp[k], m1 = nbp[k + 1], m2 = nbp[k + 2], m3 = nbp[k + 3];
            acc += p0 * h2b[(size_t)m0 * 64] + p1 * h2b[(size_t)m1 * 64]
                 + p2 * h2b[(size_t)m2 * 64] + p3 * h2b[(size_t)m3 * 64];
        }
        for (; k < K; ++k) acc += pp[k] * h2b[(size_t)nbp[k] * 64];
        xc[(size_t)row * 64 + lane] = acc;
        float v = acc * aw[lane];
#pragma unroll
        for (int mm = 1; mm < 64; mm <<= 1) v += __shfl_xor(v, mm);
        if (lane == 0) sc[row] = v;
        if (n == 0) {
            float v2 = acc * aw[64 + lane];
#pragma unroll
            for (int mm = 1; mm < 64; mm <<= 1) v2 += __shfl_xor(v2, mm);
            if (lane == 0) rootd[b] = v2;
        }
    }
    gg.sync();

    // ---------- phase 6: node softmax + pooled output (32 blocks, XCD-matched to batch) ----------
    if (blockIdx.x < NB) {
        int b = (blockIdx.x & 7) * 4 + (blockIdx.x >> 3);   // block on XCD b/4 (xc is L2-local there)
        const float* xb = xc + (size_t)b * NN * 64;
        float rd = rootd[b];
        float s = NEG_INF;
        if (t < NVALID) {
            s = sc[b * NN + t] + rd;
            if (s == 0.f) s = NEG_INF;            // masked_fill(score==0)
        }
        float mx = s;
#pragma unroll
        for (int mm = 1; mm < 64; mm <<= 1) mx = fmaxf(mx, __shfl_xor(mx, mm));
        if (lane == 0) sm.pl.red[wv] = mx;
        __syncthreads();
        mx = sm.pl.red[0];
#pragma unroll
        for (int i = 1; i < 8; ++i) mx = fmaxf(mx, sm.pl.red[i]);
        float e = (t < NN) ? __expf(s - mx) : 0.f;
        float sum = e;
#pragma unroll
        for (int mm = 1; mm < 64; mm <<= 1) sum += __shfl_xor(sum, mm);
        __syncthreads();
        if (lane == 0) sm.pl.red[wv] = sum;
        __syncthreads();
        sum = 0.f;
#pragma unroll
        for (int i = 0; i < 8; ++i) sum += sm.pl.red[i];
        float inv = 1.f / sum;
        if (t < NN) {
            float a = e * inv;
            out[NB * HIN + b * NN + t] = a;       // attn output
            sm.pl.attn[t] = a;
        }
        __syncthreads();
        float acc = 0.f;
        for (int n2 = wv; n2 < NN; n2 += 8) acc += sm.pl.attn[n2] * xb[(size_t)n2 * 64 + lane];
        sm.pl.part[wv][lane] = acc;
        __syncthreads();
        if (t < 64) {
            float v = 0.f;
#pragma unroll
            for (int i = 0; i < 8; ++i) v += sm.pl.part[i][t];
            out[b * 64 + t] = v;                  // pooled output
        }
    }
}

extern "C" void kernel_launch(void* const* d_in, const int* in_sizes, int n_in,
                              void* d_out, int out_size, void* d_ws, size_t ws_size,
                              hipStream_t stream) {
    const float* x   = (const float*)d_in[0];
    const float* A   = (const float*)d_in[1];
    const float* w1  = (const float*)d_in[4];
    const float* as1 = (const float*)d_in[5];
    const float* ad1 = (const float*)d_in[6];
    const float* w2  = (const float*)d_in[7];
    const float* as2 = (const float*)d_in[8];
    const float* ad2 = (const float*)d_in[9];
    const float* aw  = (const float*)d_in[10];
    float* out = (float*)d_out;

    char* ws = (char*)d_ws;
    int* nbr = (int*)ws;                               // [16000][128]
    int* cnt = (int*)(ws + (size_t)16000 * 128 * 4);   // [16000]
    float* f = (float*)(ws + (size_t)16000 * 129 * 4);
    float* h1p   = f;  f += (size_t)NB * NN * 128;     // [b][n][h*16+o]
    float* e1s   = f;  f += (size_t)NB * NN * 8;       // [b][n][h]
    float* e1d   = f;  f += (size_t)NB * NN * 8;
    float* h1cat = f;  f += (size_t)NB * NN * 128;
    float* h2p   = f;  f += (size_t)NB * NN * 64;
    float* e2s   = f;  f += (size_t)NB * NN;
    float* e2d   = f;  f += (size_t)NB * NN;
    float* xc    = f;  f += (size_t)NB * NN * 64;
    float* sc    = f;  f += (size_t)NB * NN;
    float* rootd = f;  f += NB;

    int occ = 0;
    hipOccupancyMaxActiveBlocksPerMultiprocessor(&occ, (const void*)k_fused, BLK, 0);
    if (occ < 1) occ = 1;
    if (occ > 4) occ = 4;
    int grid = occ * 256;

    void* args[] = { (void*)&x, (void*)&A, (void*)&w1, (void*)&as1, (void*)&ad1,
                     (void*)&w2, (void*)&as2, (void*)&ad2, (void*)&aw,
                     (void*)&nbr, (void*)&cnt, (void*)&h1p, (void*)&e1s, (void*)&e1d,
                     (void*)&h1cat, (void*)&h2p, (void*)&e2s, (void*)&e2d,
                     (void*)&xc, (void*)&sc, (void*)&rootd, (void*)&out };
    hipLaunchCooperativeKernel((const void*)k_fused, dim3(grid), dim3(BLK), args, 0, stream);
}

// Round 7
// 293.307 us; speedup vs baseline: 1.6235x; 1.6235x over previous
//
#include <hip/hip_runtime.h>

#define NB 32
#define NN 500
#define HIN 64
#define HHID 16
#define NHEAD 8
#define NVALID 400
#define MAXK 128
#define NEG_INF -1e20f

// ---------------- K0: neighbor list build (wave per row, ballot compaction) ----------------
__global__ __launch_bounds__(256) void k_nbr(const float* __restrict__ A,
                                             int* __restrict__ nbr, int* __restrict__ cnt)
{
    int row = blockIdx.x * 4 + (threadIdx.x >> 6);   // b*NN + n
    int lane = threadIdx.x & 63;
    if (row >= NB * NN) return;
    const float* arow = A + (size_t)row * NN;
    int c = 0;
    for (int it = 0; it < 8; ++it) {
        int m = it * 64 + lane;
        bool v = (m < NN) && (arow[m] > 0.0f);
        unsigned long long bal = __ballot(v);
        if (v) {
            int pos = c + __popcll(bal & ((1ull << lane) - 1ull));
            if (pos < MAXK) nbr[(size_t)row * MAXK + pos] = m;
        }
        c += (int)__popcll(bal);
    }
    if (lane == 0) cnt[row] = c < MAXK ? c : MAXK;
}

// ---------------- K1: layer-1 projection, wave per row, weights in LDS ----------------
// h1p [row][128], e1s/e1d [row][8]
__global__ __launch_bounds__(512) void k_proj1(const float* __restrict__ x, const float* __restrict__ w1,
                                               const float* __restrict__ as1, const float* __restrict__ ad1,
                                               float* __restrict__ h1p, float* __restrict__ e1s,
                                               float* __restrict__ e1d)
{
    int t = threadIdx.x, wv = t >> 6, lane = t & 63;
    __shared__ float w1s[8192];                  // [f*128 + h*16 + o]
    for (int i = t; i < 8192; i += 512) {
        int h = i >> 10, f = (i >> 4) & 63, o = i & 15;
        w1s[f * 128 + h * 16 + o] = w1[i];
    }
    float as_r[2], ad_r[2];
#pragma unroll
    for (int rr = 0; rr < 2; ++rr) { as_r[rr] = as1[rr * 64 + lane]; ad_r[rr] = ad1[rr * 64 + lane]; }
    __syncthreads();
    int gw = blockIdx.x * 8 + wv;                // 250 blocks -> 2000 waves
    for (int row = gw; row < NB * NN; row += 2000) {
        const float4* xp4 = (const float4*)(x + (size_t)row * HIN);
#pragma unroll
        for (int rr = 0; rr < 2; ++rr) {
            int oi = rr * 64 + lane;
            const float* wp = w1s + oi;
            float acc = 0.f;
#pragma unroll
            for (int f4 = 0; f4 < 16; ++f4) {
                float4 u = xp4[f4];
                acc += u.x * wp[(f4 * 4 + 0) * 128] + u.y * wp[(f4 * 4 + 1) * 128]
                     + u.z * wp[(f4 * 4 + 2) * 128] + u.w * wp[(f4 * 4 + 3) * 128];
            }
            h1p[(size_t)row * 128 + oi] = acc;
            float vs = acc * as_r[rr], vd = acc * ad_r[rr];
#pragma unroll
            for (int m = 1; m < 16; m <<= 1) { vs += __shfl_xor(vs, m); vd += __shfl_xor(vd, m); }
            if ((lane & 15) == 0) {
                int h = oi >> 4;
                e1s[(size_t)row * 8 + h] = vs;
                e1d[(size_t)row * 8 + h] = vd;
            }
        }
    }
}

// ---------------- K2: layer-1 sparse softmax + aggregate + ELU; gathers from LDS ----------------
// block = (range 0..3, half 0..1, b); stages h1p half + e1s/e1d for 4 heads
__global__ __launch_bounds__(256, 1) void k_agg1(const int* __restrict__ nbr, const int* __restrict__ cnt,
                                                 const float* __restrict__ h1p, const float* __restrict__ e1s,
                                                 const float* __restrict__ e1d, float* __restrict__ h1cat)
{
    int rng = blockIdx.x, half = blockIdx.y, b = blockIdx.z;
    int t = threadIdx.x, wv = t >> 6, lane = t & 63;
    __shared__ __align__(16) float h1_s[NN][64];     // 128 KB
    __shared__ __align__(16) float e1s_s[NN][4];     // 8 KB
    __shared__ __align__(16) float e1d_s[NN][4];     // 8 KB
    __shared__ int   nb_s[4][MAXK];                  // 2 KB
    __shared__ float p_s[4][4][132];                 // 8.25 KB (pad 132: heads hit distinct banks)
    for (int i = t; i < NN * 16; i += 256) {
        int n = i >> 4, f4 = i & 15;
        ((float4*)h1_s[n])[f4] = ((const float4*)(h1p + (size_t)(b * NN + n) * 128 + half * 64))[f4];
    }
    for (int i = t; i < NN; i += 256) {
        *(float4*)e1s_s[i] = *(const float4*)(e1s + (size_t)(b * NN + i) * 8 + half * 4);
        *(float4*)e1d_s[i] = *(const float4*)(e1d + (size_t)(b * NN + i) * 8 + half * 4);
    }
    __syncthreads();
    int n0 = rng * 125;
    for (int n = n0 + wv; n < n0 + 125; n += 4) {
        int row = b * NN + n;
        int K = cnt[row];
        const int* nbg = nbr + (size_t)row * MAXK;
        int m0 = (lane < K) ? nbg[lane] : 0;
        int m1 = (lane + 64 < K) ? nbg[lane + 64] : 0;
        nb_s[wv][lane] = m0; nb_s[wv][lane + 64] = m1;
        float4 es4 = *(const float4*)e1s_s[n];
        float4 d0 = *(const float4*)e1d_s[m0];
        float4 d1 = *(const float4*)e1d_s[m1];
        float e0[4], e1v[4];
        e0[0] = es4.x + d0.x; e0[1] = es4.y + d0.y; e0[2] = es4.z + d0.z; e0[3] = es4.w + d0.w;
        e1v[0] = es4.x + d1.x; e1v[1] = es4.y + d1.y; e1v[2] = es4.z + d1.z; e1v[3] = es4.w + d1.w;
#pragma unroll
        for (int h = 0; h < 4; ++h) {
            e0[h] = e0[h] > 0.f ? e0[h] : 0.2f * e0[h];
            e1v[h] = e1v[h] > 0.f ? e1v[h] : 0.2f * e1v[h];
            if (lane >= K) e0[h] = -1e30f;
            if (lane + 64 >= K) e1v[h] = -1e30f;
        }
#pragma unroll
        for (int h = 0; h < 4; ++h) {
            float mx = fmaxf(e0[h], e1v[h]);
#pragma unroll
            for (int mm = 1; mm < 64; mm <<= 1) mx = fmaxf(mx, __shfl_xor(mx, mm));
            float x0 = (lane < K) ? __expf(e0[h] - mx) : 0.f;
            float x1 = (lane + 64 < K) ? __expf(e1v[h] - mx) : 0.f;
            float s = x0 + x1;
#pragma unroll
            for (int mm = 1; mm < 64; mm <<= 1) s += __shfl_xor(s, mm);
            float inv = 1.f / s;
            p_s[wv][h][lane] = x0 * inv;
            p_s[wv][h][lane + 64] = x1 * inv;
        }
        const float* pp = p_s[wv][lane >> 4];
        const int* nbp = nb_s[wv];
        float acc = 0.f;
        int k = 0;
        for (; k + 4 <= K; k += 4) {
            float p0 = pp[k], p1 = pp[k + 1], p2 = pp[k + 2], p3 = pp[k + 3];
            int q0 = nbp[k], q1 = nbp[k + 1], q2 = nbp[k + 2], q3 = nbp[k + 3];
            acc += p0 * h1_s[q0][lane] + p1 * h1_s[q1][lane]
                 + p2 * h1_s[q2][lane] + p3 * h1_s[q3][lane];
        }
        for (; k < K; ++k) acc += pp[k] * h1_s[nbp[k]][lane];
        float v = acc > 0.f ? acc : expm1f(acc);      // ELU
        h1cat[(size_t)row * 128 + half * 64 + lane] = v;
    }
}

// ---------------- K3: layer-2 projection, wave per row, weights in LDS ----------------
__global__ __launch_bounds__(512) void k_proj2(const float* __restrict__ h1cat, const float* __restrict__ w2,
                                               const float* __restrict__ as2, const float* __restrict__ ad2,
                                               float* __restrict__ h2p, float* __restrict__ e2s,
                                               float* __restrict__ e2d)
{
    int t = threadIdx.x, wv = t >> 6, lane = t & 63;
    __shared__ float w2s[8192];                  // [j*64 + o]
    for (int i = t; i < 8192; i += 512) w2s[i] = w2[i];
    float as_r = as2[lane], ad_r = ad2[lane];
    __syncthreads();
    int gw = blockIdx.x * 8 + wv;
    for (int row = gw; row < NB * NN; row += 2000) {
        const float4* hp4 = (const float4*)(h1cat + (size_t)row * 128);
        const float* wp = w2s + lane;
        float acc = 0.f;
#pragma unroll 8
        for (int j4 = 0; j4 < 32; ++j4) {
            float4 u = hp4[j4];
            acc += u.x * wp[(j4 * 4 + 0) * 64] + u.y * wp[(j4 * 4 + 1) * 64]
                 + u.z * wp[(j4 * 4 + 2) * 64] + u.w * wp[(j4 * 4 + 3) * 64];
        }
        h2p[(size_t)row * 64 + lane] = acc;
        float vs = acc * as_r, vd = acc * ad_r;
#pragma unroll
        for (int m = 1; m < 64; m <<= 1) { vs += __shfl_xor(vs, m); vd += __shfl_xor(vd, m); }
        if (lane == 0) { e2s[row] = vs; e2d[row] = vd; }
    }
}

// ---------------- K4: layer-2 sparse softmax + aggregate + fused score dots; LDS-staged ----------------
// block = (range 0..7, b)
__global__ __launch_bounds__(256, 1) void k_agg2(const int* __restrict__ nbr, const int* __restrict__ cnt,
                                                 const float* __restrict__ h2p, const float* __restrict__ e2s,
                                                 const float* __restrict__ e2d, const float* __restrict__ aw,
                                                 float* __restrict__ xc, float* __restrict__ sc,
                                                 float* __restrict__ rootd)
{
    int rng = blockIdx.x, b = blockIdx.y;
    int t = threadIdx.x, wv = t >> 6, lane = t & 63;
    __shared__ __align__(16) float h2_s[NN][64];     // 128 KB
    __shared__ float e2d_s[NN];                      // 2 KB
    __shared__ int   nb_s[4][MAXK];
    __shared__ float p_s[4][MAXK];
    for (int i = t; i < NN * 16; i += 256) {
        int n = i >> 4, f4 = i & 15;
        ((float4*)h2_s[n])[f4] = ((const float4*)(h2p + (size_t)(b * NN + n) * 64))[f4];
    }
    for (int i = t; i < NN; i += 256) e2d_s[i] = e2d[b * NN + i];
    __syncthreads();
    float aw0 = aw[lane], aw64 = aw[64 + lane];
    int n0 = rng * 63, n1 = n0 + 63 < NN ? n0 + 63 : NN;
    for (int n = n0 + wv; n < n1; n += 4) {
        int row = b * NN + n;
        if (n >= NVALID) { xc[(size_t)row * 64 + lane] = 0.f; continue; }   // padded rows exactly 0
        int K = cnt[row];
        const int* nbg = nbr + (size_t)row * MAXK;
        int m0 = (lane < K) ? nbg[lane] : 0;
        int m1 = (lane + 64 < K) ? nbg[lane + 64] : 0;
        nb_s[wv][lane] = m0; nb_s[wv][lane + 64] = m1;
        float es = e2s[row];
        float e0 = -1e30f, e1v = -1e30f;
        if (lane < K)      { float e = es + e2d_s[m0]; e0 = e > 0.f ? e : 0.2f * e; }
        if (lane + 64 < K) { float e = es + e2d_s[m1]; e1v = e > 0.f ? e : 0.2f * e; }
        float mx = fmaxf(e0, e1v);
#pragma unroll
        for (int mm = 1; mm < 64; mm <<= 1) mx = fmaxf(mx, __shfl_xor(mx, mm));
        float x0 = (lane < K) ? __expf(e0 - mx) : 0.f;
        float x1 = (lane + 64 < K) ? __expf(e1v - mx) : 0.f;
        float ss = x0 + x1;
#pragma unroll
        for (int mm = 1; mm < 64; mm <<= 1) ss += __shfl_xor(ss, mm);
        float inv = 1.f / ss;
        p_s[wv][lane] = x0 * inv; p_s[wv][lane + 64] = x1 * inv;
        const float* pp = p_s[wv];
        const int* nbp = nb_s[wv];
        float acc = 0.f;
        int k = 0;
        for (; k + 4 <= K; k += 4) {
            float p0 = pp[k], p1 = pp[k + 1], p2 = pp[k + 2], p3 = pp[k + 3];
            int q0 = nbp[k], q1 = nbp[k + 1], q2 = nbp[k + 2], q3 = nbp[k + 3];
            acc += p0 * h2_s[q0][lane] + p1 * h2_s[q1][lane]
                 + p2 * h2_s[q2][lane] + p3 * h2_s[q3][lane];
        }
        for (; k < K; ++k) acc += pp[k] * h2_s[nbp[k]][lane];
        xc[(size_t)row * 64 + lane] = acc;
        float v = acc * aw0;
#pragma unroll
        for (int mm = 1; mm < 64; mm <<= 1) v += __shfl_xor(v, mm);
        if (lane == 0) sc[row] = v;
        if (n == 0) {
            float v2 = acc * aw64;
#pragma unroll
            for (int mm = 1; mm < 64; mm <<= 1) v2 += __shfl_xor(v2, mm);
            if (lane == 0) rootd[b] = v2;
        }
    }
}

// ---------------- K5: softmax over nodes + pooled output (1024 thr, 16 waves) ----------------
__global__ __launch_bounds__(1024) void k_pool(const float* __restrict__ xc, const float* __restrict__ sc,
                                               const float* __restrict__ root_dot, float* __restrict__ out)
{
    int b = blockIdx.x;
    int t = threadIdx.x, w = t >> 6, lane = t & 63;
    __shared__ float attn_s[NN];
    __shared__ float red[16];
    __shared__ float part[16][64];
    const float* xb = xc + (size_t)b * NN * 64;
    float rd = root_dot[b];
    float s = NEG_INF;
    if (t < NVALID) {
        s = sc[b * NN + t] + rd;
        if (s == 0.f) s = NEG_INF;      // masked_fill(score==0)
    }
    float mx = s;
#pragma unroll
    for (int m = 1; m < 64; m <<= 1) mx = fmaxf(mx, __shfl_xor(mx, m));
    if (lane == 0) red[w] = mx;
    __syncthreads();
    mx = red[0];
#pragma unroll
    for (int i = 1; i < 16; ++i) mx = fmaxf(mx, red[i]);
    float e = (t < NN) ? __expf(s - mx) : 0.f;
    float sum = e;
#pragma unroll
    for (int m = 1; m < 64; m <<= 1) sum += __shfl_xor(sum, m);
    __syncthreads();
    if (lane == 0) red[w] = sum;
    __syncthreads();
    sum = 0.f;
#pragma unroll
    for (int i = 0; i < 16; ++i) sum += red[i];
    float inv = 1.f / sum;
    if (t < NN) {
        float a = e * inv;
        out[NB * 64 + b * NN + t] = a;   // attn output
        attn_s[t] = a;
    }
    __syncthreads();
    float acc = 0.f;
    for (int n = w; n < NN; n += 16) acc += attn_s[n] * xb[(size_t)n * 64 + lane];
    part[w][lane] = acc;
    __syncthreads();
    if (t < 64) {
        float v = 0.f;
#pragma unroll
        for (int i = 0; i < 16; ++i) v += part[i][t];
        out[b * 64 + t] = v;
    }
}

extern "C" void kernel_launch(void* const* d_in, const int* in_sizes, int n_in,
                              void* d_out, int out_size, void* d_ws, size_t ws_size,
                              hipStream_t stream) {
    const float* x   = (const float*)d_in[0];
    const float* A   = (const float*)d_in[1];
    const float* w1  = (const float*)d_in[4];
    const float* as1 = (const float*)d_in[5];
    const float* ad1 = (const float*)d_in[6];
    const float* w2  = (const float*)d_in[7];
    const float* as2 = (const float*)d_in[8];
    const float* ad2 = (const float*)d_in[9];
    const float* aw  = (const float*)d_in[10];
    float* out = (float*)d_out;

    char* ws = (char*)d_ws;
    int* nbr = (int*)ws;                               // [16000][128]
    int* cnt = (int*)(ws + (size_t)16000 * 128 * 4);   // [16000]
    float* f = (float*)(ws + (size_t)16000 * 129 * 4);
    float* h1p   = f;  f += (size_t)NB * NN * 128;     // [row][h*16+o]
    float* e1s   = f;  f += (size_t)NB * NN * 8;       // [row][h]
    float* e1d   = f;  f += (size_t)NB * NN * 8;
    float* h1cat = f;  f += (size_t)NB * NN * 128;
    float* h2p   = f;  f += (size_t)NB * NN * 64;
    float* e2s   = f;  f += (size_t)NB * NN;
    float* e2d   = f;  f += (size_t)NB * NN;
    float* xc    = f;  f += (size_t)NB * NN * 64;
    float* sc    = f;  f += (size_t)NB * NN;
    float* rootd = f;  f += NB;

    hipLaunchKernelGGL(k_nbr,   dim3(4000),        dim3(256),  0, stream, A, nbr, cnt);
    hipLaunchKernelGGL(k_proj1, dim3(250),         dim3(512),  0, stream, x, w1, as1, ad1, h1p, e1s, e1d);
    hipLaunchKernelGGL(k_agg1,  dim3(4, 2, NB),    dim3(256),  0, stream, nbr, cnt, h1p, e1s, e1d, h1cat);
    hipLaunchKernelGGL(k_proj2, dim3(250),         dim3(512),  0, stream, h1cat, w2, as2, ad2, h2p, e2s, e2d);
    hipLaunchKernelGGL(k_agg2,  dim3(8, NB),       dim3(256),  0, stream, nbr, cnt, h2p, e2s, e2d, aw, xc, sc, rootd);
    hipLaunchKernelGGL(k_pool,  dim3(NB),          dim3(1024), 0, stream, xc, sc, rootd, out);
}

// Round 8
// 248.770 us; speedup vs baseline: 1.9141x; 1.1790x over previous
//
#include <hip/hip_runtime.h>

#define NB 32
#define NN 500
#define HIN 64
#define HHID 16
#define NHEAD 8
#define NVALID 400
#define MAXK 128
#define NEG_INF -1e20f

// ---------------- K0: fused neighbor-list build + layer-1 projection ----------------
// blocks [0,2000): nbr build, wave per row.  blocks [2000,2250): proj1, wave per row.
__global__ __launch_bounds__(512) void k_nbr_proj1(const float* __restrict__ A,
                                                   const float* __restrict__ x, const float* __restrict__ w1,
                                                   const float* __restrict__ as1, const float* __restrict__ ad1,
                                                   int* __restrict__ nbr, int* __restrict__ cnt,
                                                   float* __restrict__ h1p, float* __restrict__ e1s,
                                                   float* __restrict__ e1d)
{
    int t = threadIdx.x, wv = t >> 6, lane = t & 63;
    if (blockIdx.x < 2000) {
        int row = blockIdx.x * 8 + wv;           // 16000 rows exactly
        const float* arow = A + (size_t)row * NN;
        int c = 0;
        for (int it = 0; it < 8; ++it) {
            int m = it * 64 + lane;
            bool v = (m < NN) && (arow[m] > 0.0f);
            unsigned long long bal = __ballot(v);
            if (v) {
                int pos = c + __popcll(bal & ((1ull << lane) - 1ull));
                if (pos < MAXK) nbr[(size_t)row * MAXK + pos] = m;
            }
            c += (int)__popcll(bal);
        }
        if (lane == 0) cnt[row] = c < MAXK ? c : MAXK;
    } else {
        __shared__ float w1s[8192];              // [f*128 + h*16 + o]
        for (int i = t; i < 8192; i += 512) {
            int h = i >> 10, f = (i >> 4) & 63, o = i & 15;
            w1s[f * 128 + h * 16 + o] = w1[i];
        }
        float as_r[2], ad_r[2];
#pragma unroll
        for (int rr = 0; rr < 2; ++rr) { as_r[rr] = as1[rr * 64 + lane]; ad_r[rr] = ad1[rr * 64 + lane]; }
        __syncthreads();
        int gw = (blockIdx.x - 2000) * 8 + wv;   // 2000 waves
        for (int row = gw; row < NB * NN; row += 2000) {
            const float4* xp4 = (const float4*)(x + (size_t)row * HIN);
#pragma unroll
            for (int rr = 0; rr < 2; ++rr) {
                int oi = rr * 64 + lane;
                const float* wp = w1s + oi;
                float acc = 0.f;
#pragma unroll
                for (int f4 = 0; f4 < 16; ++f4) {
                    float4 u = xp4[f4];
                    acc += u.x * wp[(f4 * 4 + 0) * 128] + u.y * wp[(f4 * 4 + 1) * 128]
                         + u.z * wp[(f4 * 4 + 2) * 128] + u.w * wp[(f4 * 4 + 3) * 128];
                }
                h1p[(size_t)row * 128 + oi] = acc;
                float vs = acc * as_r[rr], vd = acc * ad_r[rr];
#pragma unroll
                for (int m = 1; m < 16; m <<= 1) { vs += __shfl_xor(vs, m); vd += __shfl_xor(vd, m); }
                if ((lane & 15) == 0) {
                    int h = oi >> 4;
                    e1s[(size_t)row * 8 + h] = vs;
                    e1d[(size_t)row * 8 + h] = vd;
                }
            }
        }
    }
}

// ---------------- K2: layer-1 sparse softmax (no-max) + aggregate + ELU; LDS-staged ----------------
// block = (range 0..3, half 0..1, b), 512 threads / 8 waves
__global__ __launch_bounds__(512, 1) void k_agg1(const int* __restrict__ nbr, const int* __restrict__ cnt,
                                                 const float* __restrict__ h1p, const float* __restrict__ e1s,
                                                 const float* __restrict__ e1d, float* __restrict__ h1cat)
{
    int rng = blockIdx.x, half = blockIdx.y, b = blockIdx.z;
    int t = threadIdx.x, wv = t >> 6, lane = t & 63;
    __shared__ __align__(16) float h1_s[NN][64];     // 128 KB
    __shared__ __align__(16) float e1d_s[NN][4];     // 8 KB
    __shared__ __align__(16) float p_s[8][4][136];   // 17 KB (pad 136: aligned + distinct banks per head)
    for (int i = t; i < NN * 16; i += 512) {
        int n = i >> 4, f4 = i & 15;
        ((float4*)h1_s[n])[f4] = ((const float4*)(h1p + (size_t)(b * NN + n) * 128 + half * 64))[f4];
    }
    for (int i = t; i < NN; i += 512)
        *(float4*)e1d_s[i] = *(const float4*)(e1d + (size_t)(b * NN + i) * 8 + half * 4);
    __syncthreads();
    int n0 = rng * 125;
    for (int n = n0 + wv; n < n0 + 125; n += 8) {
        int row = b * NN + n;
        int K = cnt[row];
        const int* nbg = nbr + (size_t)row * MAXK;
        int m0 = (lane < K) ? nbg[lane] : 0;
        int m1 = (lane + 64 < K) ? nbg[lane + 64] : 0;
        float4 es4 = *(const float4*)(e1s + (size_t)row * 8 + half * 4);
        float4 d0 = *(const float4*)e1d_s[m0];
        float4 d1 = *(const float4*)e1d_s[m1];
        float x0[4], x1[4];
        {
            float e;
            e = es4.x + d0.x; e = e > 0.f ? e : 0.2f * e; x0[0] = (lane < K) ? __expf(e) : 0.f;
            e = es4.y + d0.y; e = e > 0.f ? e : 0.2f * e; x0[1] = (lane < K) ? __expf(e) : 0.f;
            e = es4.z + d0.z; e = e > 0.f ? e : 0.2f * e; x0[2] = (lane < K) ? __expf(e) : 0.f;
            e = es4.w + d0.w; e = e > 0.f ? e : 0.2f * e; x0[3] = (lane < K) ? __expf(e) : 0.f;
            e = es4.x + d1.x; e = e > 0.f ? e : 0.2f * e; x1[0] = (lane + 64 < K) ? __expf(e) : 0.f;
            e = es4.y + d1.y; e = e > 0.f ? e : 0.2f * e; x1[1] = (lane + 64 < K) ? __expf(e) : 0.f;
            e = es4.z + d1.z; e = e > 0.f ? e : 0.2f * e; x1[2] = (lane + 64 < K) ? __expf(e) : 0.f;
            e = es4.w + d1.w; e = e > 0.f ? e : 0.2f * e; x1[3] = (lane + 64 < K) ? __expf(e) : 0.f;
        }
        float s[4];
#pragma unroll
        for (int h = 0; h < 4; ++h) s[h] = x0[h] + x1[h];
#pragma unroll
        for (int mm = 1; mm < 64; mm <<= 1) {     // 4 independent chains interleave
#pragma unroll
            for (int h = 0; h < 4; ++h) s[h] += __shfl_xor(s[h], mm);
        }
#pragma unroll
        for (int h = 0; h < 4; ++h) {
            float inv = 1.f / s[h];
            p_s[wv][h][lane] = x0[h] * inv;
            p_s[wv][h][lane + 64] = x1[h] * inv;
        }
        const float* pp = p_s[wv][lane >> 4];
        float acc = 0.f;
        int k = 0;
        for (; k + 4 <= K; k += 4) {
            int4 q = *(const int4*)(nbg + k);
            float4 p4 = *(const float4*)(pp + k);
            acc += p4.x * h1_s[q.x][lane] + p4.y * h1_s[q.y][lane]
                 + p4.z * h1_s[q.z][lane] + p4.w * h1_s[q.w][lane];
        }
        for (; k < K; ++k) acc += pp[k] * h1_s[nbg[k]][lane];
        float v = acc > 0.f ? acc : expm1f(acc);      // ELU
        h1cat[(size_t)row * 128 + half * 64 + lane] = v;
    }
}

// ---------------- K3: layer-2 projection, wave per row, weights in LDS ----------------
__global__ __launch_bounds__(512) void k_proj2(const float* __restrict__ h1cat, const float* __restrict__ w2,
                                               const float* __restrict__ as2, const float* __restrict__ ad2,
                                               float* __restrict__ h2p, float* __restrict__ e2s,
                                               float* __restrict__ e2d)
{
    int t = threadIdx.x, wv = t >> 6, lane = t & 63;
    __shared__ float w2s[8192];                  // [j*64 + o]
    for (int i = t; i < 8192; i += 512) w2s[i] = w2[i];
    float as_r = as2[lane], ad_r = ad2[lane];
    __syncthreads();
    int gw = blockIdx.x * 8 + wv;
    for (int row = gw; row < NB * NN; row += 2000) {
        const float4* hp4 = (const float4*)(h1cat + (size_t)row * 128);
        const float* wp = w2s + lane;
        float acc = 0.f;
#pragma unroll 8
        for (int j4 = 0; j4 < 32; ++j4) {
            float4 u = hp4[j4];
            acc += u.x * wp[(j4 * 4 + 0) * 64] + u.y * wp[(j4 * 4 + 1) * 64]
                 + u.z * wp[(j4 * 4 + 2) * 64] + u.w * wp[(j4 * 4 + 3) * 64];
        }
        h2p[(size_t)row * 64 + lane] = acc;
        float vs = acc * as_r, vd = acc * ad_r;
#pragma unroll
        for (int m = 1; m < 64; m <<= 1) { vs += __shfl_xor(vs, m); vd += __shfl_xor(vd, m); }
        if (lane == 0) { e2s[row] = vs; e2d[row] = vd; }
    }
}

// ---------------- K4: layer-2 sparse softmax (no-max) + aggregate + fused score dots ----------------
// block = (range 0..7, b), 512 threads / 8 waves
__global__ __launch_bounds__(512, 1) void k_agg2(const int* __restrict__ nbr, const int* __restrict__ cnt,
                                                 const float* __restrict__ h2p, const float* __restrict__ e2s,
                                                 const float* __restrict__ e2d, const float* __restrict__ aw,
                                                 float* __restrict__ xc, float* __restrict__ sc,
                                                 float* __restrict__ rootd)
{
    int rng = blockIdx.x, b = blockIdx.y;
    int t = threadIdx.x, wv = t >> 6, lane = t & 63;
    __shared__ __align__(16) float h2_s[NN][64];     // 128 KB
    __shared__ float e2d_s[NN];                      // 2 KB
    __shared__ float p_s[8][MAXK];                   // 4 KB
    for (int i = t; i < NN * 16; i += 512) {
        int n = i >> 4, f4 = i & 15;
        ((float4*)h2_s[n])[f4] = ((const float4*)(h2p + (size_t)(b * NN + n) * 64))[f4];
    }
    for (int i = t; i < NN; i += 512) e2d_s[i] = e2d[b * NN + i];
    __syncthreads();
    float aw0 = aw[lane], aw64 = aw[64 + lane];
    int n0 = rng * 63, n1 = n0 + 63 < NN ? n0 + 63 : NN;
    for (int n = n0 + wv; n < n1; n += 8) {
        int row = b * NN + n;
        if (n >= NVALID) { xc[(size_t)row * 64 + lane] = 0.f; continue; }   // padded rows exactly 0
        int K = cnt[row];
        const int* nbg = nbr + (size_t)row * MAXK;
        int m0 = (lane < K) ? nbg[lane] : 0;
        int m1 = (lane + 64 < K) ? nbg[lane + 64] : 0;
        float es = e2s[row];
        float x0 = 0.f, x1 = 0.f;
        if (lane < K)      { float e = es + e2d_s[m0]; e = e > 0.f ? e : 0.2f * e; x0 = __expf(e); }
        if (lane + 64 < K) { float e = es + e2d_s[m1]; e = e > 0.f ? e : 0.2f * e; x1 = __expf(e); }
        float ss = x0 + x1;
#pragma unroll
        for (int mm = 1; mm < 64; mm <<= 1) ss += __shfl_xor(ss, mm);
        float inv = 1.f / ss;
        p_s[wv][lane] = x0 * inv; p_s[wv][lane + 64] = x1 * inv;
        const float* pp = p_s[wv];
        float acc = 0.f;
        int k = 0;
        for (; k + 4 <= K; k += 4) {
            int4 q = *(const int4*)(nbg + k);
            float4 p4 = *(const float4*)(pp + k);
            acc += p4.x * h2_s[q.x][lane] + p4.y * h2_s[q.y][lane]
                 + p4.z * h2_s[q.z][lane] + p4.w * h2_s[q.w][lane];
        }
        for (; k < K; ++k) acc += pp[k] * h2_s[nbg[k]][lane];
        xc[(size_t)row * 64 + lane] = acc;
        float v = acc * aw0;
#pragma unroll
        for (int mm = 1; mm < 64; mm <<= 1) v += __shfl_xor(v, mm);
        if (lane == 0) sc[row] = v;
        if (n == 0) {
            float v2 = acc * aw64;
#pragma unroll
            for (int mm = 1; mm < 64; mm <<= 1) v2 += __shfl_xor(v2, mm);
            if (lane == 0) rootd[b] = v2;
        }
    }
}

// ---------------- K5: softmax over nodes + pooled output (1024 thr, 16 waves) ----------------
__global__ __launch_bounds__(1024) void k_pool(const float* __restrict__ xc, const float* __restrict__ sc,
                                               const float* __restrict__ root_dot, float* __restrict__ out)
{
    int b = blockIdx.x;
    int t = threadIdx.x, w = t >> 6, lane = t & 63;
    __shared__ float attn_s[NN];
    __shared__ float red[16];
    __shared__ float part[16][64];
    const float* xb = xc + (size_t)b * NN * 64;
    float rd = root_dot[b];
    float s = NEG_INF;
    if (t < NVALID) {
        s = sc[b * NN + t] + rd;
        if (s == 0.f) s = NEG_INF;      // masked_fill(score==0)
    }
    float mx = s;
#pragma unroll
    for (int m = 1; m < 64; m <<= 1) mx = fmaxf(mx, __shfl_xor(mx, m));
    if (lane == 0) red[w] = mx;
    __syncthreads();
    mx = red[0];
#pragma unroll
    for (int i = 1; i < 16; ++i) mx = fmaxf(mx, red[i]);
    float e = (t < NN) ? __expf(s - mx) : 0.f;
    float sum = e;
#pragma unroll
    for (int m = 1; m < 64; m <<= 1) sum += __shfl_xor(sum, m);
    __syncthreads();
    if (lane == 0) red[w] = sum;
    __syncthreads();
    sum = 0.f;
#pragma unroll
    for (int i = 0; i < 16; ++i) sum += red[i];
    float inv = 1.f / sum;
    if (t < NN) {
        float a = e * inv;
        out[NB * 64 + b * NN + t] = a;   // attn output
        attn_s[t] = a;
    }
    __syncthreads();
    float acc = 0.f;
    for (int n = w; n < NN; n += 16) acc += attn_s[n] * xb[(size_t)n * 64 + lane];
    part[w][lane] = acc;
    __syncthreads();
    if (t < 64) {
        float v = 0.f;
#pragma unroll
        for (int i = 0; i < 16; ++i) v += part[i][t];
        out[b * 64 + t] = v;
    }
}

extern "C" void kernel_launch(void* const* d_in, const int* in_sizes, int n_in,
                              void* d_out, int out_size, void* d_ws, size_t ws_size,
                              hipStream_t stream) {
    const float* x   = (const float*)d_in[0];
    const float* A   = (const float*)d_in[1];
    const float* w1  = (const float*)d_in[4];
    const float* as1 = (const float*)d_in[5];
    const float* ad1 = (const float*)d_in[6];
    const float* w2  = (const float*)d_in[7];
    const float* as2 = (const float*)d_in[8];
    const float* ad2 = (const float*)d_in[9];
    const float* aw  = (const float*)d_in[10];
    float* out = (float*)d_out;

    char* ws = (char*)d_ws;
    int* nbr = (int*)ws;                               // [16000][128]
    int* cnt = (int*)(ws + (size_t)16000 * 128 * 4);   // [16000]
    float* f = (float*)(ws + (size_t)16000 * 129 * 4);
    float* h1p   = f;  f += (size_t)NB * NN * 128;     // [row][h*16+o]
    float* e1s   = f;  f += (size_t)NB * NN * 8;       // [row][h]
    float* e1d   = f;  f += (size_t)NB * NN * 8;
    float* h1cat = f;  f += (size_t)NB * NN * 128;
    float* h2p   = f;  f += (size_t)NB * NN * 64;
    float* e2s   = f;  f += (size_t)NB * NN;
    float* e2d   = f;  f += (size_t)NB * NN;
    float* xc    = f;  f += (size_t)NB * NN * 64;
    float* sc    = f;  f += (size_t)NB * NN;
    float* rootd = f;  f += NB;

    hipLaunchKernelGGL(k_nbr_proj1, dim3(2250),     dim3(512),  0, stream,
                       A, x, w1, as1, ad1, nbr, cnt, h1p, e1s, e1d);
    hipLaunchKernelGGL(k_agg1,      dim3(4, 2, NB), dim3(512),  0, stream, nbr, cnt, h1p, e1s, e1d, h1cat);
    hipLaunchKernelGGL(k_proj2,     dim3(250),      dim3(512),  0, stream, h1cat, w2, as2, ad2, h2p, e2s, e2d);
    hipLaunchKernelGGL(k_agg2,      dim3(8, NB),    dim3(512),  0, stream, nbr, cnt, h2p, e2s, e2d, aw, xc, sc, rootd);
    hipLaunchKernelGGL(k_pool,      dim3(NB),       dim3(1024), 0, stream, xc, sc, rootd, out);
}